// Round 6
// baseline (66.264 us; speedup 1.0000x reference)
//
#include <hip/hip_runtime.h>

// Shapes (fixed): T=8, S=512, B=8, D=512, H=8, hd=64, BH=64, NE=32, NI=64.
// out: (64, 512, 512) f32.
//
// Math reduction: sum_p telescopes to (sum_t Q_t)(sum_t K_t)^T * scale, so
//   p = (Xsum@Wq^T + 8 bq)(Xsum@Wk^T + 8 bk)^T / 64   (per bh batch, hd=64)
// The 1/64 is folded into Q at projection time.
//
// Q/K are stored in MFMA-FRAGMENT ORDER: [bh][blk16][half][lane][16B], so
// k_attn operand loads are fully-coalesced 1KB dwordx4 reads.
//
// exp-MLP epilogue = piecewise-linear in tp (32 ReLU knots): 4096-bucket
// uniform chord LUT over [-20,3], built on-device from the exact f32 MLP.
// k_attn uses light 256-thread blocks, 4 co-resident per CU; tmax is
// computed per-wave (extra col-block-0 MFMA) + shfl broadcast -> no barrier
// on the critical path before the epilogue. Output stores non-temporal.

#define T_  8
#define NE_ 32
#define NI_ 64

#define LUT_N   4096
#define LUT_LO  -20.0f
#define LUT_HI  3.0f
#define LUT_INVW (LUT_N / (LUT_HI - LUT_LO))     // 4096/23
#define LUT_W    ((LUT_HI - LUT_LO) / LUT_N)

typedef __attribute__((ext_vector_type(8))) short bf16x8;
typedef __attribute__((ext_vector_type(4))) float f32x4;

// workspace layout, in ushort elements
#define XS_OFF 0u        // Xsum bf16 (4096 x 512)
#define WQ_OFF 2097152u  // Wq bf16 (512 x 512)
#define WK_OFF 2359296u  // Wk bf16
#define QB_OFF 2621440u  // Q bf16 frag-order (64*32*2*1024B), pre-scaled 1/64
#define KB_OFF 4718592u  // K bf16 frag-order
#define LUT_OFF 6815744u // float2 lut[4096] = 32 KB

__device__ inline unsigned short f2bf(float f) {
  union { float f; unsigned u; } v; v.f = f;
  unsigned r = v.u + 0x7FFFu + ((v.u >> 16) & 1u);
  return (unsigned short)(r >> 16);
}

__device__ inline void gload16(const void* g, void* l) {
  __builtin_amdgcn_global_load_lds(
      (const __attribute__((address_space(1))) void*)g,
      (__attribute__((address_space(3))) void*)l, 16, 0, 0);
}

// XOR-swizzled LDS read (k_proj only): 128-byte rows, slot ^ (row&7)
__device__ inline bf16x8 lds_read_swz(const unsigned short* base, int row, int byteoff) {
  int addr = row * 128 + (byteoff ^ ((row & 7) << 4));
  return *(const bf16x8*)((const char*)base + addr);
}

__device__ inline float invmlp(float x, const float* __restrict__ w1,
                               const float* __restrict__ b1,
                               const float* __restrict__ w2, float b2) {
  float a = b2;
#pragma unroll 8
  for (int n = 0; n < NI_; n++) a += w2[n] * fmaxf(x * w1[n] + b1[n], 0.0f);
  return a;
}

__device__ inline float expmlp_exact(float t, const float* __restrict__ w1,
                                     const float* __restrict__ b1,
                                     const float* __restrict__ w2, float b2) {
  float a = b2;
#pragma unroll
  for (int n = 0; n < NE_; n++) a += w2[n] * fmaxf(t * w1[n] + b1[n], 0.0f);
  return a;
}

// ---------------------------------------------------------------------------
// Kernel 1: Xsum = sum_t sx[t] (f32->bf16), Wq/Wk casts, exp-MLP chord LUT.
__global__ __launch_bounds__(256) void k_pre(
    const float* __restrict__ sx, const float* __restrict__ wq,
    const float* __restrict__ wk, const float* __restrict__ ew1,
    const float* __restrict__ eb1, const float* __restrict__ ew2,
    const float* __restrict__ eb2p,
    unsigned short* __restrict__ xs, unsigned short* __restrict__ wqb,
    unsigned short* __restrict__ wkb, float2* __restrict__ lut) {
  int bx = blockIdx.x, tid = threadIdx.x;
  if (bx < 2048) {
    size_t i = ((size_t)bx * 256 + tid) * 4;
    float4 a = *(const float4*)(sx + i);
#pragma unroll
    for (int t = 1; t < T_; t++) {
      float4 v = *(const float4*)(sx + (size_t)t * 2097152 + i);
      a.x += v.x; a.y += v.y; a.z += v.z; a.w += v.w;
    }
    ushort4 o; o.x = f2bf(a.x); o.y = f2bf(a.y); o.z = f2bf(a.z); o.w = f2bf(a.w);
    *(ushort4*)(xs + i) = o;
  } else if (bx < 2560) {
    const float* src = (bx < 2304) ? wq : wk;
    unsigned short* dst = (bx < 2304) ? wqb : wkb;
    int base = (bx < 2304) ? 2048 : 2304;
    size_t i = ((size_t)(bx - base) * 256 + tid) * 4;
    float4 a = *(const float4*)(src + i);
    ushort4 o; o.x = f2bf(a.x); o.y = f2bf(a.y); o.z = f2bf(a.z); o.w = f2bf(a.w);
    *(ushort4*)(dst + i) = o;
  } else {
    // chord LUT: bucket i over [t_i, t_{i+1}]; edges evaluated identically by
    // neighbors -> bit-exact continuity.
    int i = (bx - 2560) * 256 + tid;
    float b2 = eb2p[0];
    float tl = fmaf((float)i, LUT_W, LUT_LO);
    float th = fmaf((float)(i + 1), LUT_W, LUT_LO);
    float el = expmlp_exact(tl, ew1, eb1, ew2, b2);
    float eh = expmlp_exact(th, ew1, eb1, ew2, b2);
    float alpha = (eh - el) * LUT_INVW;
    float beta = fmaf(-alpha, tl, el);
    lut[i] = make_float2(alpha, beta);
  }
}

// ---------------------------------------------------------------------------
// Kernel 2: Y = Xsum(4096x512) @ W^T + 8*bias -> bf16 in FRAG-ORDER layout.
// z=0 (Q) additionally scaled by 1/64.  grid (32,4,2), 256 thr, 128x128 tile.
__global__ __launch_bounds__(256, 2) void k_proj(
    const unsigned short* __restrict__ xs, const unsigned short* __restrict__ wb,
    const float* __restrict__ bq, const float* __restrict__ bk,
    unsigned short* __restrict__ outb) {
  __shared__ unsigned short As[128 * 64];
  __shared__ unsigned short Bs[128 * 64];
  int tid = threadIdx.x;
  int lane = tid & 63, w = tid >> 6;
  int r0 = blockIdx.x * 128;
  int c0 = blockIdx.y * 128;
  int z = blockIdx.z;
  const unsigned short* W = wb + (size_t)z * 262144;
  const float* bias = z ? bk : bq;
  unsigned short* dst = outb + (size_t)z * 2097152;
  float sc = z ? 1.0f : (1.0f / 64.0f);

  int rgrp = lane >> 4, cl = lane & 15;
  int r0w = (w >> 1) * 64, c0w = (w & 1) * 64;

  f32x4 acc[4][4];
  f32x4 zero = {0.f, 0.f, 0.f, 0.f};
#pragma unroll
  for (int m = 0; m < 4; m++)
#pragma unroll
    for (int n = 0; n < 4; n++) acc[m][n] = zero;

  int rl = lane >> 3, slot = lane & 7;

  for (int kt = 0; kt < 8; kt++) {
    int k0 = kt * 64;
#pragma unroll
    for (int i = 0; i < 4; i++) {
      int chunk = w * 4 + i;
      int r = chunk * 8 + rl;
      int sw = (slot ^ (r & 7)) * 8;
      gload16(xs + (size_t)(r0 + r) * 512 + k0 + sw, (char*)As + chunk * 1024);
      gload16(W + (size_t)(c0 + r) * 512 + k0 + sw, (char*)Bs + chunk * 1024);
    }
    __syncthreads();
#pragma unroll
    for (int kb = 0; kb < 2; kb++) {
      bf16x8 af[4], bfr[4];
#pragma unroll
      for (int m = 0; m < 4; m++) af[m] = lds_read_swz(As, r0w + 16 * m + cl, kb * 64 + rgrp * 16);
#pragma unroll
      for (int n = 0; n < 4; n++) bfr[n] = lds_read_swz(Bs, c0w + 16 * n + cl, kb * 64 + rgrp * 16);
#pragma unroll
      for (int m = 0; m < 4; m++)
#pragma unroll
        for (int n = 0; n < 4; n++)
          acc[m][n] = __builtin_amdgcn_mfma_f32_16x16x32_bf16(af[m], bfr[n], acc[m][n], 0, 0, 0);
    }
    __syncthreads();
  }

  // epilogue: +8*bias, scale, cast, scatter into frag-order layout
#pragma unroll
  for (int n = 0; n < 4; n++) {
    int cg = c0 + c0w + 16 * n + cl;          // Y col = (h, dh)
    float bv = 8.0f * bias[cg];
    int h = cg >> 6, dh = cg & 63;
    int chunk = dh >> 3, hh = chunk >> 2, rg2 = chunk & 3, jj = dh & 7;
#pragma unroll
    for (int m = 0; m < 4; m++) {
#pragma unroll
      for (int j = 0; j < 4; j++) {
        int rg = r0 + r0w + 16 * m + rgrp * 4 + j;  // Y row = (s, b)
        int s = rg >> 3, b = rg & 7;
        int bh = b * 8 + h;
        int cb = s >> 4, cls = s & 15;
        size_t idx = ((size_t)((bh * 32 + cb) * 2 + hh)) * 512 + (rg2 * 16 + cls) * 8 + jj;
        dst[idx] = f2bf((acc[m][n][j] + bv) * sc);
      }
    }
  }
}

// ---------------------------------------------------------------------------
// Kernel 3: per (32-row tile, bh): P = Q K^T (Q pre-scaled), LUT epilogue.
// grid 1024 blocks x 256 thr (4 waves), exactly 4 blocks/CU co-resident.
// XCD-chunked: block i -> XCD i&7 owns bh range [xcd*8,+8).
// wave = (rs = w&1: 16-row stripe) x (ch = w>>1: 256-col strip), acc[16].
// tmax: every wave computes col-block 0 itself + shfl broadcast (no barrier).
__global__ __launch_bounds__(256, 4) void k_attn(
    const unsigned short* __restrict__ qb, const unsigned short* __restrict__ kb,
    const float2* __restrict__ lutg,
    const float* __restrict__ iw1, const float* __restrict__ ib1,
    const float* __restrict__ iw2, const float* __restrict__ ib2p,
    float* __restrict__ out) {
  __shared__ float2 Lut[LUT_N];   // 32 KB
  __shared__ float s_part[2][32];
  __shared__ float s_fac[32];

  int tid = threadIdx.x;
  int lane = tid & 63, w = tid >> 6;
  int i = blockIdx.x;
  int xcd = i & 7, j2 = i >> 3;        // j2 in [0,128)
  int bh = xcd * 8 + (j2 >> 4);
  int rt = j2 & 15;                    // 32-row tile index
  int rs = w & 1, ch = w >> 1;
  int rgrp = lane >> 4, cl = lane & 15;

  // stage LUT into LDS (4 waves x 8 chunks of 1 KB, linear); the barrier that
  // publishes it sits AFTER the whole MFMA phase, so latency is hidden.
#pragma unroll
  for (int c = 0; c < 8; c++) {
    int chunk = w * 8 + c;
    gload16((const char*)lutg + chunk * 1024 + lane * 16, (char*)Lut + chunk * 1024);
  }

  // Q A-fragments for this wave's 16 rows (1KB coalesced each)
  int rb = rt * 2 + rs;
  const char* Qb = (const char*)qb + (size_t)((bh * 32 + rb) * 2) * 1024;
  bf16x8 aF0 = *(const bf16x8*)(Qb + lane * 16);
  bf16x8 aF1 = *(const bf16x8*)(Qb + 1024 + lane * 16);

  const char* Kbase = (const char*)kb + (size_t)(bh * 32) * 2048;
  f32x4 zero = {0.f, 0.f, 0.f, 0.f};

  // col-block 0 (for tmax) — computed by every wave
  f32x4 p0;
  {
    bf16x8 b0 = *(const bf16x8*)(Kbase + lane * 16);
    bf16x8 b1 = *(const bf16x8*)(Kbase + 1024 + lane * 16);
    p0 = __builtin_amdgcn_mfma_f32_16x16x32_bf16(aF0, b0, zero, 0, 0, 0);
    p0 = __builtin_amdgcn_mfma_f32_16x16x32_bf16(aF1, b1, p0, 0, 0, 0);
  }

  f32x4 acc[16];
#pragma unroll
  for (int f = 0; f < 16; f++) {
    const char* Kb = Kbase + (size_t)(ch * 16 + f) * 2048;
    bf16x8 b0 = *(const bf16x8*)(Kb + lane * 16);
    bf16x8 b1 = *(const bf16x8*)(Kb + 1024 + lane * 16);
    acc[f] = __builtin_amdgcn_mfma_f32_16x16x32_bf16(aF0, b0, zero, 0, 0, 0);
    acc[f] = __builtin_amdgcn_mfma_f32_16x16x32_bf16(aF1, b1, acc[f], 0, 0, 0);
  }

  // tmax - 1: broadcast P[row][0] from the cl==0 lane of each 16-lane group
  int src = lane & 48;
  float tm1[4];
#pragma unroll
  for (int j = 0; j < 4; j++) tm1[j] = __shfl(p0[j], src) - 1.0f;

  __syncthreads();  // LUT visible (gloads landed during MFMA phase)

  const float C0 = -LUT_LO * LUT_INVW;
  float rowsum[4] = {0.f, 0.f, 0.f, 0.f};
#pragma unroll
  for (int f = 0; f < 16; f++) {
#pragma unroll
    for (int j = 0; j < 4; j++) {
      float tp = fminf(acc[f][j] - tm1[j], 3.0f);
      float u = fmaf(tp, LUT_INVW, C0);
      u = fminf(fmaxf(u, 0.0f), (float)(LUT_N - 1));  // v_med3
      float2 ab = Lut[(int)u];
      float xu = fmaf(ab.x, tp, ab.y);
      xu = (tp > -20.0f) ? xu : 0.0f;
      acc[f][j] = xu;
      rowsum[j] += xu;
    }
  }

  // row partial sums across the 16 cl lanes
#pragma unroll
  for (int j = 0; j < 4; j++) {
    float s = rowsum[j];
    s += __shfl_xor(s, 1);
    s += __shfl_xor(s, 2);
    s += __shfl_xor(s, 4);
    s += __shfl_xor(s, 8);
    if (cl == 0) s_part[ch][rs * 16 + rgrp * 4 + j] = s;
  }
  __syncthreads();

  if (tid < 32) {
    float part = s_part[0][tid] + s_part[1][tid];
    float pinv = invmlp(part, iw1, ib1, iw2, ib2p[0]);
    float pp2 = part * pinv;
    float fac = pinv;
    if (pp2 > 1.5f) fac *= invmlp(pp2, iw1, ib1, iw2, ib2p[0]);
    s_fac[tid] = fac;
  }
  __syncthreads();

  float* outb = out + ((size_t)bh * 512 + rt * 32) * 512;
#pragma unroll
  for (int j = 0; j < 4; j++) {
    int row = rs * 16 + rgrp * 4 + j;
    float fac = s_fac[row];
#pragma unroll
    for (int f = 0; f < 16; f++)
      __builtin_nontemporal_store(acc[f][j] * fac,
          &outb[(size_t)row * 512 + ch * 256 + 16 * f + cl]);
  }
}

extern "C" void kernel_launch(void* const* d_in, const int* in_sizes, int n_in,
                              void* d_out, int out_size, void* d_ws, size_t ws_size,
                              hipStream_t stream) {
  (void)in_sizes; (void)n_in; (void)out_size; (void)ws_size;
  const float* sx  = (const float*)d_in[0];
  const float* wq  = (const float*)d_in[1];
  const float* wk  = (const float*)d_in[2];
  const float* bq  = (const float*)d_in[3];
  const float* bk  = (const float*)d_in[4];
  const float* ew1 = (const float*)d_in[5];
  const float* eb1 = (const float*)d_in[6];
  const float* ew2 = (const float*)d_in[7];
  const float* eb2 = (const float*)d_in[8];
  const float* iw1 = (const float*)d_in[9];
  const float* ib1 = (const float*)d_in[10];
  const float* iw2 = (const float*)d_in[11];
  const float* ib2 = (const float*)d_in[12];
  unsigned short* wsu = (unsigned short*)d_ws;
  float2* lut = (float2*)(wsu + LUT_OFF);
  float* out = (float*)d_out;

  k_pre<<<2576, 256, 0, stream>>>(sx, wq, wk, ew1, eb1, ew2, eb2,
                                  wsu + XS_OFF, wsu + WQ_OFF, wsu + WK_OFF, lut);
  k_proj<<<dim3(32, 4, 2), 256, 0, stream>>>(wsu + XS_OFF, wsu + WQ_OFF, bq, bk, wsu + QB_OFF);
  k_attn<<<1024, 256, 0, stream>>>(wsu + QB_OFF, wsu + KB_OFF, lut,
                                   iw1, ib1, iw2, ib2, out);
}

// Round 7
// 55.469 us; speedup vs baseline: 1.1946x; 1.1946x over previous
//
#include <hip/hip_runtime.h>

// Shapes (fixed): T=8, S=512, B=8, D=512, H=8, hd=64, BH=64, NE=32, NI=64.
// out: (64, 512, 512) f32.
//
// Math reduction: sum_p telescopes to (sum_t Q_t)(sum_t K_t)^T * scale, so
//   p = (Xsum@Wq^T + 8 bq)(Xsum@Wk^T + 8 bk)^T / 64   (per bh batch, hd=64)
// The 1/64 is folded into Q at projection time.
//
// Q/K are stored in MFMA-FRAGMENT ORDER: [bh][blk16][half][lane][16B], so
// k_attn operand loads are fully-coalesced 1KB dwordx4 reads.
//
// exp-MLP epilogue = piecewise-linear in tp (32 ReLU knots): 4096-bucket
// uniform chord LUT over [-20,3], built on-device from the exact f32 MLP.
//
// k_attn register budget (the R4/R6 lesson): VGPR+AGPR share one 128-reg
// budget at 4 blocks/CU. acc[8] (32 AGPR) + ~65 VGPR fits; acc[16]+extras
// (132) spilled ~200B/thread to scratch (+52MB HBM writes). Keep it lean.

#define T_  8
#define NE_ 32
#define NI_ 64

#define LUT_N   4096
#define LUT_LO  -20.0f
#define LUT_HI  3.0f
#define LUT_INVW (LUT_N / (LUT_HI - LUT_LO))     // 4096/23
#define LUT_W    ((LUT_HI - LUT_LO) / LUT_N)

typedef __attribute__((ext_vector_type(8))) short bf16x8;
typedef __attribute__((ext_vector_type(4))) float f32x4;

// workspace layout, in ushort elements
#define XS_OFF 0u        // Xsum bf16 (4096 x 512)
#define WQ_OFF 2097152u  // Wq bf16 (512 x 512)
#define WK_OFF 2359296u  // Wk bf16
#define QB_OFF 2621440u  // Q bf16 frag-order (64*32*2*1024B), pre-scaled 1/64
#define KB_OFF 4718592u  // K bf16 frag-order
#define LUT_OFF 6815744u // float2 lut[4096] = 32 KB

__device__ inline unsigned short f2bf(float f) {
  union { float f; unsigned u; } v; v.f = f;
  unsigned r = v.u + 0x7FFFu + ((v.u >> 16) & 1u);
  return (unsigned short)(r >> 16);
}

__device__ inline void gload16(const void* g, void* l) {
  __builtin_amdgcn_global_load_lds(
      (const __attribute__((address_space(1))) void*)g,
      (__attribute__((address_space(3))) void*)l, 16, 0, 0);
}

// XOR-swizzled LDS read (k_proj only): 128-byte rows, slot ^ (row&7)
__device__ inline bf16x8 lds_read_swz(const unsigned short* base, int row, int byteoff) {
  int addr = row * 128 + (byteoff ^ ((row & 7) << 4));
  return *(const bf16x8*)((const char*)base + addr);
}

__device__ inline float invmlp(float x, const float* __restrict__ w1,
                               const float* __restrict__ b1,
                               const float* __restrict__ w2, float b2) {
  float a = b2;
#pragma unroll 8
  for (int n = 0; n < NI_; n++) a += w2[n] * fmaxf(x * w1[n] + b1[n], 0.0f);
  return a;
}

__device__ inline float expmlp_exact(float t, const float* __restrict__ w1,
                                     const float* __restrict__ b1,
                                     const float* __restrict__ w2, float b2) {
  float a = b2;
#pragma unroll
  for (int n = 0; n < NE_; n++) a += w2[n] * fmaxf(t * w1[n] + b1[n], 0.0f);
  return a;
}

// ---------------------------------------------------------------------------
// Kernel 1: Xsum = sum_t sx[t] (f32->bf16), Wq/Wk casts, exp-MLP chord LUT.
__global__ __launch_bounds__(256) void k_pre(
    const float* __restrict__ sx, const float* __restrict__ wq,
    const float* __restrict__ wk, const float* __restrict__ ew1,
    const float* __restrict__ eb1, const float* __restrict__ ew2,
    const float* __restrict__ eb2p,
    unsigned short* __restrict__ xs, unsigned short* __restrict__ wqb,
    unsigned short* __restrict__ wkb, float2* __restrict__ lut) {
  int bx = blockIdx.x, tid = threadIdx.x;
  if (bx < 2048) {
    size_t i = ((size_t)bx * 256 + tid) * 4;
    float4 a = *(const float4*)(sx + i);
#pragma unroll
    for (int t = 1; t < T_; t++) {
      float4 v = *(const float4*)(sx + (size_t)t * 2097152 + i);
      a.x += v.x; a.y += v.y; a.z += v.z; a.w += v.w;
    }
    ushort4 o; o.x = f2bf(a.x); o.y = f2bf(a.y); o.z = f2bf(a.z); o.w = f2bf(a.w);
    *(ushort4*)(xs + i) = o;
  } else if (bx < 2560) {
    const float* src = (bx < 2304) ? wq : wk;
    unsigned short* dst = (bx < 2304) ? wqb : wkb;
    int base = (bx < 2304) ? 2048 : 2304;
    size_t i = ((size_t)(bx - base) * 256 + tid) * 4;
    float4 a = *(const float4*)(src + i);
    ushort4 o; o.x = f2bf(a.x); o.y = f2bf(a.y); o.z = f2bf(a.z); o.w = f2bf(a.w);
    *(ushort4*)(dst + i) = o;
  } else {
    // chord LUT: bucket i over [t_i, t_{i+1}]; edges evaluated identically by
    // neighbors -> bit-exact continuity.
    int i = (bx - 2560) * 256 + tid;
    float b2 = eb2p[0];
    float tl = fmaf((float)i, LUT_W, LUT_LO);
    float th = fmaf((float)(i + 1), LUT_W, LUT_LO);
    float el = expmlp_exact(tl, ew1, eb1, ew2, b2);
    float eh = expmlp_exact(th, ew1, eb1, ew2, b2);
    float alpha = (eh - el) * LUT_INVW;
    float beta = fmaf(-alpha, tl, el);
    lut[i] = make_float2(alpha, beta);
  }
}

// ---------------------------------------------------------------------------
// Kernel 2: Y = Xsum(4096x512) @ W^T + 8*bias -> bf16 in FRAG-ORDER layout.
// z=0 (Q) additionally scaled by 1/64.  grid (32,4,2), 256 thr, 128x128 tile.
__global__ __launch_bounds__(256, 2) void k_proj(
    const unsigned short* __restrict__ xs, const unsigned short* __restrict__ wb,
    const float* __restrict__ bq, const float* __restrict__ bk,
    unsigned short* __restrict__ outb) {
  __shared__ unsigned short As[128 * 64];
  __shared__ unsigned short Bs[128 * 64];
  int tid = threadIdx.x;
  int lane = tid & 63, w = tid >> 6;
  int r0 = blockIdx.x * 128;
  int c0 = blockIdx.y * 128;
  int z = blockIdx.z;
  const unsigned short* W = wb + (size_t)z * 262144;
  const float* bias = z ? bk : bq;
  unsigned short* dst = outb + (size_t)z * 2097152;
  float sc = z ? 1.0f : (1.0f / 64.0f);

  int rgrp = lane >> 4, cl = lane & 15;
  int r0w = (w >> 1) * 64, c0w = (w & 1) * 64;

  f32x4 acc[4][4];
  f32x4 zero = {0.f, 0.f, 0.f, 0.f};
#pragma unroll
  for (int m = 0; m < 4; m++)
#pragma unroll
    for (int n = 0; n < 4; n++) acc[m][n] = zero;

  int rl = lane >> 3, slot = lane & 7;

  for (int kt = 0; kt < 8; kt++) {
    int k0 = kt * 64;
#pragma unroll
    for (int i = 0; i < 4; i++) {
      int chunk = w * 4 + i;
      int r = chunk * 8 + rl;
      int sw = (slot ^ (r & 7)) * 8;
      gload16(xs + (size_t)(r0 + r) * 512 + k0 + sw, (char*)As + chunk * 1024);
      gload16(W + (size_t)(c0 + r) * 512 + k0 + sw, (char*)Bs + chunk * 1024);
    }
    __syncthreads();
#pragma unroll
    for (int kb = 0; kb < 2; kb++) {
      bf16x8 af[4], bfr[4];
#pragma unroll
      for (int m = 0; m < 4; m++) af[m] = lds_read_swz(As, r0w + 16 * m + cl, kb * 64 + rgrp * 16);
#pragma unroll
      for (int n = 0; n < 4; n++) bfr[n] = lds_read_swz(Bs, c0w + 16 * n + cl, kb * 64 + rgrp * 16);
#pragma unroll
      for (int m = 0; m < 4; m++)
#pragma unroll
        for (int n = 0; n < 4; n++)
          acc[m][n] = __builtin_amdgcn_mfma_f32_16x16x32_bf16(af[m], bfr[n], acc[m][n], 0, 0, 0);
    }
    __syncthreads();
  }

  // epilogue: +8*bias, scale, cast, scatter into frag-order layout
#pragma unroll
  for (int n = 0; n < 4; n++) {
    int cg = c0 + c0w + 16 * n + cl;          // Y col = (h, dh)
    float bv = 8.0f * bias[cg];
    int h = cg >> 6, dh = cg & 63;
    int chunk = dh >> 3, hh = chunk >> 2, rg2 = chunk & 3, jj = dh & 7;
#pragma unroll
    for (int m = 0; m < 4; m++) {
#pragma unroll
      for (int j = 0; j < 4; j++) {
        int rg = r0 + r0w + 16 * m + rgrp * 4 + j;  // Y row = (s, b)
        int s = rg >> 3, b = rg & 7;
        int bh = b * 8 + h;
        int cb = s >> 4, cls = s & 15;
        size_t idx = ((size_t)((bh * 32 + cb) * 2 + hh)) * 512 + (rg2 * 16 + cls) * 8 + jj;
        dst[idx] = f2bf((acc[m][n][j] + bv) * sc);
      }
    }
  }
}

// ---------------------------------------------------------------------------
// Kernel 3: per (16-row block rb, bh): P = Q K^T (Q pre-scaled), LUT epilogue.
// grid 2048 blocks x 256 thr (4 waves); wave w owns a 128-col strip, acc[8]
// (32 AGPR -> total regs ~100, no spill at 4 blocks/CU).
// XCD-chunked: block i -> XCD i&7 owns bh range [xcd*8,+8).
// tmax: every wave computes col-block 0 (+2 MFMA) + shfl broadcast; the only
// pre-epilogue barrier is the LUT publish, placed after the MFMA phase.
__global__ __launch_bounds__(256, 4) void k_attn(
    const unsigned short* __restrict__ qb, const unsigned short* __restrict__ kb,
    const float2* __restrict__ lutg,
    const float* __restrict__ iw1, const float* __restrict__ ib1,
    const float* __restrict__ iw2, const float* __restrict__ ib2p,
    float* __restrict__ out) {
  __shared__ float2 Lut[LUT_N];   // 32 KB
  __shared__ float s_part[4][16];
  __shared__ float s_fac[16];

  int tid = threadIdx.x;
  int lane = tid & 63, w = tid >> 6;   // w = 128-col strip
  int i = blockIdx.x;
  int xcd = i & 7, j2 = i >> 3;        // j2 in [0,256)
  int bh = xcd * 8 + (j2 >> 5);
  int rb = j2 & 31;                    // 16-row block
  int rgrp = lane >> 4, cl = lane & 15;

  // stage LUT into LDS (4 waves x 8 chunks of 1 KB, linear); published by the
  // barrier AFTER the MFMA phase, so the gloads land under compute.
#pragma unroll
  for (int c = 0; c < 8; c++) {
    int chunk = w * 8 + c;
    gload16((const char*)lutg + chunk * 1024 + lane * 16, (char*)Lut + chunk * 1024);
  }

  // Q A-fragments for this block's 16 rows (1KB coalesced each)
  const char* Qb = (const char*)qb + (size_t)((bh * 32 + rb) * 2) * 1024;
  bf16x8 aF0 = *(const bf16x8*)(Qb + lane * 16);
  bf16x8 aF1 = *(const bf16x8*)(Qb + 1024 + lane * 16);

  const char* Kbase = (const char*)kb + (size_t)(bh * 32) * 2048;
  f32x4 zero = {0.f, 0.f, 0.f, 0.f};

  // col-block 0 (for tmax), every wave; p0 is transient (regs reused after)
  float tm1[4];
  {
    bf16x8 b0 = *(const bf16x8*)(Kbase + lane * 16);
    bf16x8 b1 = *(const bf16x8*)(Kbase + 1024 + lane * 16);
    f32x4 p0 = __builtin_amdgcn_mfma_f32_16x16x32_bf16(aF0, b0, zero, 0, 0, 0);
    p0 = __builtin_amdgcn_mfma_f32_16x16x32_bf16(aF1, b1, p0, 0, 0, 0);
    int src = lane & 48;  // cl==0 lane of this rgrp group
#pragma unroll
    for (int j = 0; j < 4; j++) tm1[j] = __shfl(p0[j], src) - 1.0f;
  }

  f32x4 acc[8];
#pragma unroll
  for (int f = 0; f < 8; f++) {
    const char* Kb = Kbase + (size_t)(w * 8 + f) * 2048;
    bf16x8 b0 = *(const bf16x8*)(Kb + lane * 16);
    bf16x8 b1 = *(const bf16x8*)(Kb + 1024 + lane * 16);
    acc[f] = __builtin_amdgcn_mfma_f32_16x16x32_bf16(aF0, b0, zero, 0, 0, 0);
    acc[f] = __builtin_amdgcn_mfma_f32_16x16x32_bf16(aF1, b1, acc[f], 0, 0, 0);
  }

  __syncthreads();  // LUT visible (gloads landed during MFMA phase)

  const float C0 = -LUT_LO * LUT_INVW;
  float rowsum[4] = {0.f, 0.f, 0.f, 0.f};
#pragma unroll
  for (int f = 0; f < 8; f++) {
#pragma unroll
    for (int j = 0; j < 4; j++) {
      float tp = fminf(acc[f][j] - tm1[j], 3.0f);
      float u = fmaf(tp, LUT_INVW, C0);
      u = fminf(fmaxf(u, 0.0f), (float)(LUT_N - 1));  // v_med3
      float2 ab = Lut[(int)u];
      float xu = fmaf(ab.x, tp, ab.y);
      xu = (tp > -20.0f) ? xu : 0.0f;
      acc[f][j] = xu;
      rowsum[j] += xu;
    }
  }

  // row partial sums across the 16 cl lanes
#pragma unroll
  for (int j = 0; j < 4; j++) {
    float s = rowsum[j];
    s += __shfl_xor(s, 1);
    s += __shfl_xor(s, 2);
    s += __shfl_xor(s, 4);
    s += __shfl_xor(s, 8);
    if (cl == 0) s_part[w][rgrp * 4 + j] = s;
  }
  __syncthreads();

  if (tid < 16) {
    float part = s_part[0][tid] + s_part[1][tid] + s_part[2][tid] + s_part[3][tid];
    float pinv = invmlp(part, iw1, ib1, iw2, ib2p[0]);
    float pp2 = part * pinv;
    float fac = pinv;
    if (pp2 > 1.5f) fac *= invmlp(pp2, iw1, ib1, iw2, ib2p[0]);
    s_fac[tid] = fac;
  }
  __syncthreads();

  float* outb = out + ((size_t)bh * 512 + rb * 16) * 512;
#pragma unroll
  for (int j = 0; j < 4; j++) {
    int row = rgrp * 4 + j;
    float fac = s_fac[row];
#pragma unroll
    for (int f = 0; f < 8; f++)
      __builtin_nontemporal_store(acc[f][j] * fac,
          &outb[(size_t)row * 512 + w * 128 + 16 * f + cl]);
  }
}

extern "C" void kernel_launch(void* const* d_in, const int* in_sizes, int n_in,
                              void* d_out, int out_size, void* d_ws, size_t ws_size,
                              hipStream_t stream) {
  (void)in_sizes; (void)n_in; (void)out_size; (void)ws_size;
  const float* sx  = (const float*)d_in[0];
  const float* wq  = (const float*)d_in[1];
  const float* wk  = (const float*)d_in[2];
  const float* bq  = (const float*)d_in[3];
  const float* bk  = (const float*)d_in[4];
  const float* ew1 = (const float*)d_in[5];
  const float* eb1 = (const float*)d_in[6];
  const float* ew2 = (const float*)d_in[7];
  const float* eb2 = (const float*)d_in[8];
  const float* iw1 = (const float*)d_in[9];
  const float* ib1 = (const float*)d_in[10];
  const float* iw2 = (const float*)d_in[11];
  const float* ib2 = (const float*)d_in[12];
  unsigned short* wsu = (unsigned short*)d_ws;
  float2* lut = (float2*)(wsu + LUT_OFF);
  float* out = (float*)d_out;

  k_pre<<<2576, 256, 0, stream>>>(sx, wq, wk, ew1, eb1, ew2, eb2,
                                  wsu + XS_OFF, wsu + WQ_OFF, wsu + WK_OFF, lut);
  k_proj<<<dim3(32, 4, 2), 256, 0, stream>>>(wsu + XS_OFF, wsu + WQ_OFF, bq, bk, wsu + QB_OFF);
  k_attn<<<2048, 256, 0, stream>>>(wsu + QB_OFF, wsu + KB_OFF, lut,
                                   iw1, ib1, iw2, ib2, out);
}